// Round 7
// baseline (986.355 us; speedup 1.0000x reference)
//
#include <hip/hip_runtime.h>
#include <stdint.h>

#define N_NODES 50000
#define N_EDGES 800000
#define NGROUPS ((N_NODES + 3) / 4)

typedef __bf16 bf16x8 __attribute__((ext_vector_type(8)));
typedef float f32x4 __attribute__((ext_vector_type(4)));

__device__ __forceinline__ unsigned short f2bf(float f) {
  union { float f; unsigned int i; } x; x.f = f;
  unsigned int i = x.i;
  unsigned int r = (i + 0x7fffu + ((i >> 16) & 1u)) >> 16;  // round-nearest-even
  return (unsigned short)r;
}
__device__ __forceinline__ unsigned int pk2bf(float a, float b) {
  return (unsigned int)f2bf(a) | ((unsigned int)f2bf(b) << 16);
}
__device__ __forceinline__ float bfl(unsigned int p) {
  union { unsigned int i; float f; } x; x.i = p << 16; return x.f;
}
__device__ __forceinline__ float bfh(unsigned int p) {
  union { unsigned int i; float f; } x; x.i = p & 0xffff0000u; return x.f;
}

// ---------------------------------------------------------------------------
// Weight transpose+convert: W f32 [k=128][n=128] -> Wt bf16 [n][k].
// ---------------------------------------------------------------------------
struct Ptr8 { const float* p[8]; };

__global__ __launch_bounds__(256) void transpose_w(Ptr8 ws, unsigned short* wt) {
  int mat = blockIdx.x;
  const float* W = ws.p[mat];
  unsigned short* out = wt + mat * 16384;
  for (int it = 0; it < 64; ++it) {
    int idx = it * 256 + threadIdx.x;
    int n = idx >> 7, k = idx & 127;
    out[n * 128 + k] = f2bf(W[k * 128 + n]);
  }
}

// ---------------------------------------------------------------------------
// CSR build (cnt/cursor zeroed via hipMemsetAsync)
// ---------------------------------------------------------------------------
__global__ void hist_kernel(const int* __restrict__ dst, int* __restrict__ cnt) {
  int e = blockIdx.x * blockDim.x + threadIdx.x;
  if (e < N_EDGES) atomicAdd(&cnt[dst[e]], 1);
}

__global__ __launch_bounds__(1024) void scan_kernel(const int* __restrict__ cnt, int* __restrict__ rs) {
  const int n = N_NODES, per = 49;
  int t = threadIdx.x;
  int lo = t * per; int hi = lo + per;
  if (lo > n) lo = n;
  if (hi > n) hi = n;
  int s = 0;
  for (int i = lo; i < hi; ++i) s += cnt[i];
  int lane = t & 63, wv = t >> 6;
  int v = s;
  #pragma unroll
  for (int off = 1; off < 64; off <<= 1) {
    int u = __shfl_up(v, off, 64);
    if (lane >= off) v += u;
  }
  __shared__ int wsum[16], woff[16];
  if (lane == 63) wsum[wv] = v;
  __syncthreads();
  if (t == 0) { int a = 0; for (int w = 0; w < 16; ++w) { woff[w] = a; a += wsum[w]; } }
  __syncthreads();
  int run = woff[wv] + (v - s);
  if (t == 0) rs[0] = 0;
  for (int i = lo; i < hi; ++i) { run += cnt[i]; rs[i + 1] = run; }
}

// scatter + fused edge_attr CSR gather (f32 -> bf16)
__global__ void scatter_kernel(const int* __restrict__ src, const int* __restrict__ dst,
                               const float* __restrict__ EA,
                               const int* __restrict__ rs, int* __restrict__ cursor,
                               int* __restrict__ srcArr, unsigned short* __restrict__ eacsr) {
  int e = blockIdx.x * blockDim.x + threadIdx.x;
  if (e < N_EDGES) {
    int d = dst[e];
    int pos = rs[d] + atomicAdd(&cursor[d], 1);
    srcArr[pos] = src[e];
    const float4* p = (const float4*)(EA + (size_t)e * 16);
    float4 r0 = p[0], r1 = p[1], r2 = p[2], r3 = p[3];
    uint4 u0 = { pk2bf(r0.x, r0.y), pk2bf(r0.z, r0.w), pk2bf(r1.x, r1.y), pk2bf(r1.z, r1.w) };
    uint4 u1 = { pk2bf(r2.x, r2.y), pk2bf(r2.z, r2.w), pk2bf(r3.x, r3.y), pk2bf(r3.z, r3.w) };
    *(uint4*)(eacsr + (size_t)pos * 16) = u0;
    *(uint4*)(eacsr + (size_t)pos * 16 + 8) = u1;
  }
}

// ---------------------------------------------------------------------------
// Merged node GEMM: {q,k,v,s} = X @ {Wq,Wk,Wv,Ws} + b in ONE dispatch.
// X staged once; k,v written interleaved: kvb[row*256 + (col>>1)*4 + (col&1)
// + (isV?2:0)] so attn reads one uint2 per edge per lane.
// ---------------------------------------------------------------------------
struct Gemm4Args {
  const float* Xf;
  const unsigned short* Xh;
  const unsigned short* Wt;
  const float* b[4];
  unsigned short* qb;
  unsigned short* kvb;
  unsigned short* sb;
  int M;
};

template<bool XF32>
__global__ __launch_bounds__(256) void node_gemm4(Gemm4Args ga) {
  __shared__ alignas(16) unsigned short At[128 * 128];
  __shared__ alignas(16) unsigned short Bt[128 * 128];
  int m0 = blockIdx.x * 128;
  int lane = threadIdx.x & 63, wv = threadIdx.x >> 6;
  int wm = wv >> 1, wn = wv & 1;
  int lr = lane & 15, lk = lane >> 4;

  #pragma unroll
  for (int it = 0; it < 8; ++it) {
    int c = it * 256 + threadIdx.x;
    int row = c >> 4, slot = c & 15;
    int dsl = slot ^ (row & 7);
    int grow = m0 + row; if (grow >= ga.M) grow = ga.M - 1;
    alignas(16) unsigned short tmp[8];
    if (XF32) {
      const float* xp = ga.Xf + (size_t)grow * 128 + slot * 8;
      float4 a = *(const float4*)xp;
      float4 b = *(const float4*)(xp + 4);
      tmp[0] = f2bf(a.x); tmp[1] = f2bf(a.y); tmp[2] = f2bf(a.z); tmp[3] = f2bf(a.w);
      tmp[4] = f2bf(b.x); tmp[5] = f2bf(b.y); tmp[6] = f2bf(b.z); tmp[7] = f2bf(b.w);
    } else {
      *(uint4*)tmp = *(const uint4*)(ga.Xh + (size_t)grow * 128 + slot * 8);
    }
    *(uint4*)(&At[row * 128 + dsl * 8]) = *(const uint4*)tmp;
  }

  #pragma unroll
  for (int which = 0; which < 4; ++which) {
    if (which) __syncthreads();
    const unsigned short* Wt = ga.Wt + which * 16384;
    #pragma unroll
    for (int it = 0; it < 8; ++it) {
      int c = it * 256 + threadIdx.x;
      int row = c >> 4, slot = c & 15;
      int dsl = slot ^ (row & 7);
      *(uint4*)(&Bt[row * 128 + dsl * 8]) = *(const uint4*)(Wt + c * 8);
    }
    __syncthreads();

    f32x4 acc[4][4];
    #pragma unroll
    for (int mi = 0; mi < 4; ++mi)
      #pragma unroll
      for (int ni = 0; ni < 4; ++ni) acc[mi][ni] = (f32x4){0.f, 0.f, 0.f, 0.f};

    #pragma unroll
    for (int kk = 0; kk < 4; ++kk) {
      bf16x8 af[4], bfr[4];
      #pragma unroll
      for (int mi = 0; mi < 4; ++mi) {
        int row = wm * 64 + mi * 16 + lr;
        int slot = (kk * 4 + lk) ^ (row & 7);
        af[mi] = *(const bf16x8*)(&At[row * 128 + slot * 8]);
      }
      #pragma unroll
      for (int ni = 0; ni < 4; ++ni) {
        int row = wn * 64 + ni * 16 + lr;
        int slot = (kk * 4 + lk) ^ (row & 7);
        bfr[ni] = *(const bf16x8*)(&Bt[row * 128 + slot * 8]);
      }
      #pragma unroll
      for (int mi = 0; mi < 4; ++mi)
        #pragma unroll
        for (int ni = 0; ni < 4; ++ni)
          acc[mi][ni] = __builtin_amdgcn_mfma_f32_16x16x32_bf16(af[mi], bfr[ni], acc[mi][ni], 0, 0, 0);
    }

    const float* bias = ga.b[which];
    float bv[4];
    #pragma unroll
    for (int ni = 0; ni < 4; ++ni) bv[ni] = bias[wn * 64 + ni * 16 + lr];
    #pragma unroll
    for (int mi = 0; mi < 4; ++mi) {
      #pragma unroll
      for (int i = 0; i < 4; ++i) {
        int row = m0 + wm * 64 + mi * 16 + lk * 4 + i;
        if (row < ga.M) {
          #pragma unroll
          for (int ni = 0; ni < 4; ++ni) {
            int col = wn * 64 + ni * 16 + lr;
            unsigned short val = f2bf(acc[mi][ni][i] + bv[ni]);
            if (which == 0)      ga.qb[(size_t)row * 128 + col] = val;
            else if (which == 3) ga.sb[(size_t)row * 128 + col] = val;
            else ga.kvb[(size_t)row * 256 + (size_t)(col >> 1) * 4 + (col & 1) + (which == 2 ? 2 : 0)] = val;
          }
        }
      }
    }
  }
}

// ---------------------------------------------------------------------------
// Per-dst-node fused attention v5: grid-stride persistent blocks, interleaved
// kv uint2 gathers, JIT ep stream loads, factored edge-MLP, 8-edge chunks.
// __launch_bounds__(256,8): cap VGPR at 64 for 8 waves/SIMD.
// ---------------------------------------------------------------------------
template<int CHALF, bool RELU, bool OUT_BF16>
__global__ __launch_bounds__(256, 8) void edge_attn(
    const unsigned short* __restrict__ Q, const uint2* __restrict__ KV,
    const unsigned short* __restrict__ S, const float* __restrict__ We,
    const unsigned short* __restrict__ EAC,
    const int* __restrict__ srcArr, const int* __restrict__ rs,
    void* __restrict__ outv, float inv_sqrt_c) {
  int wv = threadIdx.x >> 6, lane = threadIdx.x & 63;
  int c0 = lane * 2;
  int jbase = (lane & 1) * 8 + ((lane >> 1) & 1) * 4 + ((lane >> 2) & 1) * 2;

  for (int ng = blockIdx.x; ng < NGROUPS; ng += gridDim.x) {
    int node = ng * 4 + wv;
    if (node >= N_NODES) continue;

    unsigned int qp = *(const unsigned int*)(Q + (size_t)node * 128 + c0);
    float qa = bfl(qp) * inv_sqrt_c;
    float qb = bfh(qp) * inv_sqrt_c;

    // qWe[j] reduce-scatter over lane bits 0..2
    float part[16];
    #pragma unroll
    for (int j = 0; j < 16; ++j) {
      float2 wp = *(const float2*)(We + j * 128 + c0);
      part[j] = qa * wp.x + qb * wp.y;
    }
    {
      bool hi = lane & 1;
      #pragma unroll
      for (int j = 0; j < 8; ++j) {
        float kept = hi ? part[j + 8] : part[j];
        float sent = hi ? part[j] : part[j + 8];
        part[j] = kept + __shfl_xor(sent, 1, 64);
      }
      hi = lane & 2;
      #pragma unroll
      for (int j = 0; j < 4; ++j) {
        float kept = hi ? part[j + 4] : part[j];
        float sent = hi ? part[j] : part[j + 4];
        part[j] = kept + __shfl_xor(sent, 2, 64);
      }
      hi = lane & 4;
      #pragma unroll
      for (int j = 0; j < 2; ++j) {
        float kept = hi ? part[j + 2] : part[j];
        float sent = hi ? part[j] : part[j + 2];
        part[j] = kept + __shfl_xor(sent, 4, 64);
      }
    }
    if (CHALF == 64) {
      #pragma unroll
      for (int s = 8; s <= 32; s <<= 1) {
        part[0] += __shfl_xor(part[0], s, 64);
        part[1] += __shfl_xor(part[1], s, 64);
      }
    }
    float qw0 = part[0] * (CHALF == 64 ? 0.125f : 1.0f);
    float qw1 = part[1] * (CHALF == 64 ? 0.125f : 1.0f);

    int i0 = rs[node], i1 = rs[node + 1];
    int deg = i1 - i0;
    float den = 0.f, a0 = 0.f, a1 = 0.f, wea0 = 0.f, wea1 = 0.f;

    struct Buf { uint2 kv[8]; };
    Buf bA, bB;
    int svA = 0, svB = 0;

    auto load_src = [&](int c) -> int {
      return srcArr[i0 + c * 8 + (lane & 7)];
    };
    auto gather = [&](Buf& b, int sv) {
      #pragma unroll
      for (int j = 0; j < 8; ++j) {
        int s = __shfl(sv, j, 8);
        b.kv[j] = KV[(size_t)s * 64 + lane];
      }
    };
    auto compute = [&](const Buf& b, int c) {
      #pragma unroll
      for (int j = 0; j < 8; ++j) {
        int g = i0 + c * 8 + j;
        unsigned int ep = *(const unsigned int*)(EAC + (size_t)g * 16 + jbase);
        float ea0 = bfl(ep), ea1 = bfh(ep);
        float p = qa * bfl(b.kv[j].x) + qb * bfh(b.kv[j].x) + qw0 * ea0 + qw1 * ea1;
        #pragma unroll
        for (int off = 1; off < CHALF; off <<= 1) p += __shfl_xor(p, off, 64);
        float w = (g < i1) ? __expf(p) : 0.f;
        den  += w;
        a0   += w * bfl(b.kv[j].y);
        a1   += w * bfh(b.kv[j].y);
        wea0 += w * ea0;
        wea1 += w * ea1;
      }
    };

    int nch = (deg + 7) >> 3;
    if (nch > 0) {
      svA = load_src(0);
      if (nch > 1) svB = load_src(1);
      gather(bA, svA);
      int c = 0;
      while (true) {
        if (c + 1 < nch) gather(bB, svB);
        if (c + 2 < nch) svA = load_src(c + 2);
        compute(bA, c);
        ++c; if (c >= nch) break;
        if (c + 1 < nch) gather(bA, svA);
        if (c + 2 < nch) svB = load_src(c + 2);
        compute(bB, c);
        ++c; if (c >= nch) break;
      }
    }

    // epilogue: (a + wea@We)/den + skip
    float inv = 1.f / (den + 1e-16f);
    float eadd0 = 0.f, eadd1 = 0.f;
    #pragma unroll
    for (int j = 0; j < 16; ++j) {
      int owner = ((j >> 3) & 1) | (((j >> 2) & 1) << 1) | (((j >> 1) & 1) << 2);
      int srcl = (lane & 56) | owner;
      float val = __shfl((j & 1) ? wea1 : wea0, srcl, 64);
      float2 wp = *(const float2*)(We + j * 128 + c0);
      eadd0 += val * wp.x;
      eadd1 += val * wp.y;
    }
    unsigned int sp = *(const unsigned int*)(S + (size_t)node * 128 + c0);
    float o0 = (a0 + eadd0) * inv + bfl(sp);
    float o1 = (a1 + eadd1) * inv + bfh(sp);
    if (RELU) { o0 = fmaxf(o0, 0.f); o1 = fmaxf(o1, 0.f); }
    if (OUT_BF16) {
      unsigned int op = ((unsigned int)f2bf(o1) << 16) | (unsigned int)f2bf(o0);
      *(unsigned int*)((unsigned short*)outv + (size_t)node * 128 + c0) = op;
    } else {
      *(float2*)((float*)outv + (size_t)node * 128 + c0) = make_float2(o0, o1);
    }
  }
}

// ---------------------------------------------------------------------------
extern "C" void kernel_launch(void* const* d_in, const int* in_sizes, int n_in,
                              void* d_out, int out_size, void* d_ws, size_t ws_size,
                              hipStream_t stream) {
  const float* x   = (const float*)d_in[0];
  const int*   ei  = (const int*)d_in[1];
  const float* ea  = (const float*)d_in[2];
  const float* Wq0 = (const float*)d_in[3];
  const float* bq0 = (const float*)d_in[4];
  const float* Wk0 = (const float*)d_in[5];
  const float* bk0 = (const float*)d_in[6];
  const float* Wv0 = (const float*)d_in[7];
  const float* bv0 = (const float*)d_in[8];
  const float* We0 = (const float*)d_in[9];
  const float* Ws0 = (const float*)d_in[10];
  const float* bs0 = (const float*)d_in[11];
  const float* Wq1 = (const float*)d_in[12];
  const float* bq1 = (const float*)d_in[13];
  const float* Wk1 = (const float*)d_in[14];
  const float* bk1 = (const float*)d_in[15];
  const float* Wv1 = (const float*)d_in[16];
  const float* bv1 = (const float*)d_in[17];
  const float* We1 = (const float*)d_in[18];
  const float* Ws1 = (const float*)d_in[19];
  const float* bs1 = (const float*)d_in[20];

  char* ws = (char*)d_ws;
  size_t off = 0;
  auto alloc = [&](size_t bytes) -> void* {
    void* p = ws + off;
    off = (off + bytes + 255) & ~(size_t)255;
    return p;
  };
  unsigned short* WT    = (unsigned short*)alloc(8 * 16384 * 2);
  unsigned short* q     = (unsigned short*)alloc((size_t)N_NODES * 128 * 2);
  unsigned short* kvb   = (unsigned short*)alloc((size_t)N_NODES * 256 * 2);
  unsigned short* s     = (unsigned short*)alloc((size_t)N_NODES * 128 * 2);
  unsigned short* h     = (unsigned short*)alloc((size_t)N_NODES * 128 * 2);
  unsigned short* eacsr = (unsigned short*)alloc(((size_t)N_EDGES + 8) * 16 * 2);
  int* cc     = (int*)alloc((size_t)2 * N_NODES * 4);      // cnt | cursor
  int* rs     = (int*)alloc((N_NODES + 1) * 4);
  int* srcArr = (int*)alloc(((size_t)N_EDGES + 8) * 4);
  int* cnt = cc, *cursor = cc + N_NODES;
  // total ~94 MB

  const int* srcp = ei;
  const int* dstp = ei + N_EDGES;

  hipMemsetAsync(cc, 0, (size_t)2 * N_NODES * 4, stream);
  hipMemsetAsync(srcArr + N_EDGES, 0, 8 * 4, stream);
  hipMemsetAsync(eacsr + (size_t)N_EDGES * 16, 0, 8 * 16 * 2, stream);

  Ptr8 p8 = {{Wq0, Wk0, Wv0, Ws0, Wq1, Wk1, Wv1, Ws1}};
  transpose_w<<<8, 256, 0, stream>>>(p8, WT);
  hist_kernel<<<3125, 256, 0, stream>>>(dstp, cnt);
  scan_kernel<<<1, 1024, 0, stream>>>(cnt, rs);
  scatter_kernel<<<3125, 256, 0, stream>>>(srcp, dstp, ea, rs, cursor, srcArr, eacsr);

  // layer 0
  Gemm4Args ga0 = { x, nullptr, WT, {bq0, bk0, bv0, bs0}, q, kvb, s, N_NODES };
  node_gemm4<true><<<391, 256, 0, stream>>>(ga0);
  edge_attn<8, true, true><<<2048, 256, 0, stream>>>(q, (const uint2*)kvb, s, We0, eacsr,
                                                     srcArr, rs, h, 0.25f);

  // layer 1
  Gemm4Args ga1 = { nullptr, h, WT + 4 * 16384, {bq1, bk1, bv1, bs1}, q, kvb, s, N_NODES };
  node_gemm4<false><<<391, 256, 0, stream>>>(ga1);
  edge_attn<64, false, false><<<2048, 256, 0, stream>>>(q, (const uint2*)kvb, s, We1, eacsr,
                                                        srcArr, rs, d_out, 0.08838834764831845f);
}

// Round 9
// 655.418 us; speedup vs baseline: 1.5049x; 1.5049x over previous
//
#include <hip/hip_runtime.h>
#include <stdint.h>

#define N_NODES 50000
#define N_EDGES 800000
#define NGROUPS (N_NODES / 4)   // 12500, exact

typedef __bf16 bf16x8 __attribute__((ext_vector_type(8)));
typedef float f32x4 __attribute__((ext_vector_type(4)));

__device__ __forceinline__ unsigned short f2bf(float f) {
  union { float f; unsigned int i; } x; x.f = f;
  unsigned int i = x.i;
  unsigned int r = (i + 0x7fffu + ((i >> 16) & 1u)) >> 16;  // round-nearest-even
  return (unsigned short)r;
}
__device__ __forceinline__ unsigned int pk2bf(float a, float b) {
  return (unsigned int)f2bf(a) | ((unsigned int)f2bf(b) << 16);
}
__device__ __forceinline__ float bfl(unsigned int p) {
  union { unsigned int i; float f; } x; x.i = p << 16; return x.f;
}
__device__ __forceinline__ float bfh(unsigned int p) {
  union { unsigned int i; float f; } x; x.i = p & 0xffff0000u; return x.f;
}

// ---------------------------------------------------------------------------
// Weight transpose+convert: W f32 [k=128][n=128] -> Wt bf16 [n][k].
// ---------------------------------------------------------------------------
struct Ptr8 { const float* p[8]; };

__global__ __launch_bounds__(256) void transpose_w(Ptr8 ws, unsigned short* wt) {
  int mat = blockIdx.x;
  const float* W = ws.p[mat];
  unsigned short* out = wt + mat * 16384;
  for (int it = 0; it < 64; ++it) {
    int idx = it * 256 + threadIdx.x;
    int n = idx >> 7, k = idx & 127;
    out[n * 128 + k] = f2bf(W[k * 128 + n]);
  }
}

// ---------------------------------------------------------------------------
// CSR build (cnt/cursor zeroed via hipMemsetAsync)
// ---------------------------------------------------------------------------
__global__ void hist_kernel(const int* __restrict__ dst, int* __restrict__ cnt) {
  int e = blockIdx.x * blockDim.x + threadIdx.x;
  if (e < N_EDGES) atomicAdd(&cnt[dst[e]], 1);
}

__global__ __launch_bounds__(1024) void scan_kernel(const int* __restrict__ cnt, int* __restrict__ rs) {
  const int n = N_NODES, per = 49;
  int t = threadIdx.x;
  int lo = t * per; int hi = lo + per;
  if (lo > n) lo = n;
  if (hi > n) hi = n;
  int s = 0;
  for (int i = lo; i < hi; ++i) s += cnt[i];
  int lane = t & 63, wv = t >> 6;
  int v = s;
  #pragma unroll
  for (int off = 1; off < 64; off <<= 1) {
    int u = __shfl_up(v, off, 64);
    if (lane >= off) v += u;
  }
  __shared__ int wsum[16], woff[16];
  if (lane == 63) wsum[wv] = v;
  __syncthreads();
  if (t == 0) { int a = 0; for (int w = 0; w < 16; ++w) { woff[w] = a; a += wsum[w]; } }
  __syncthreads();
  int run = woff[wv] + (v - s);
  if (t == 0) rs[0] = 0;
  for (int i = lo; i < hi; ++i) { run += cnt[i]; rs[i + 1] = run; }
}

// scatter + fused edge_attr CSR gather (f32 -> bf16)
__global__ void scatter_kernel(const int* __restrict__ src, const int* __restrict__ dst,
                               const float* __restrict__ EA,
                               const int* __restrict__ rs, int* __restrict__ cursor,
                               int* __restrict__ srcArr, unsigned short* __restrict__ eacsr) {
  int e = blockIdx.x * blockDim.x + threadIdx.x;
  if (e < N_EDGES) {
    int d = dst[e];
    int pos = rs[d] + atomicAdd(&cursor[d], 1);
    srcArr[pos] = src[e];
    const float4* p = (const float4*)(EA + (size_t)e * 16);
    float4 r0 = p[0], r1 = p[1], r2 = p[2], r3 = p[3];
    uint4 u0 = { pk2bf(r0.x, r0.y), pk2bf(r0.z, r0.w), pk2bf(r1.x, r1.y), pk2bf(r1.z, r1.w) };
    uint4 u1 = { pk2bf(r2.x, r2.y), pk2bf(r2.z, r2.w), pk2bf(r3.x, r3.y), pk2bf(r3.z, r3.w) };
    *(uint4*)(eacsr + (size_t)pos * 16) = u0;
    *(uint4*)(eacsr + (size_t)pos * 16 + 8) = u1;
  }
}

// ---------------------------------------------------------------------------
// Merged node GEMM: {q,k,v,s} = X @ {Wq,Wk,Wv,Ws} + b in ONE dispatch.
// X staged once; k,v written interleaved: kvb[row*256 + (col>>1)*4 + (col&1)
// + (isV?2:0)] so attn reads one uint2 per edge per lane.
// ---------------------------------------------------------------------------
struct Gemm4Args {
  const float* Xf;
  const unsigned short* Xh;
  const unsigned short* Wt;
  const float* b[4];
  unsigned short* qb;
  unsigned short* kvb;
  unsigned short* sb;
  int M;
};

template<bool XF32>
__global__ __launch_bounds__(256) void node_gemm4(Gemm4Args ga) {
  __shared__ alignas(16) unsigned short At[128 * 128];
  __shared__ alignas(16) unsigned short Bt[128 * 128];
  int m0 = blockIdx.x * 128;
  int lane = threadIdx.x & 63, wv = threadIdx.x >> 6;
  int wm = wv >> 1, wn = wv & 1;
  int lr = lane & 15, lk = lane >> 4;

  #pragma unroll
  for (int it = 0; it < 8; ++it) {
    int c = it * 256 + threadIdx.x;
    int row = c >> 4, slot = c & 15;
    int dsl = slot ^ (row & 7);
    int grow = m0 + row; if (grow >= ga.M) grow = ga.M - 1;
    alignas(16) unsigned short tmp[8];
    if (XF32) {
      const float* xp = ga.Xf + (size_t)grow * 128 + slot * 8;
      float4 a = *(const float4*)xp;
      float4 b = *(const float4*)(xp + 4);
      tmp[0] = f2bf(a.x); tmp[1] = f2bf(a.y); tmp[2] = f2bf(a.z); tmp[3] = f2bf(a.w);
      tmp[4] = f2bf(b.x); tmp[5] = f2bf(b.y); tmp[6] = f2bf(b.z); tmp[7] = f2bf(b.w);
    } else {
      *(uint4*)tmp = *(const uint4*)(ga.Xh + (size_t)grow * 128 + slot * 8);
    }
    *(uint4*)(&At[row * 128 + dsl * 8]) = *(const uint4*)tmp;
  }

  #pragma unroll
  for (int which = 0; which < 4; ++which) {
    if (which) __syncthreads();
    const unsigned short* Wt = ga.Wt + which * 16384;
    #pragma unroll
    for (int it = 0; it < 8; ++it) {
      int c = it * 256 + threadIdx.x;
      int row = c >> 4, slot = c & 15;
      int dsl = slot ^ (row & 7);
      *(uint4*)(&Bt[row * 128 + dsl * 8]) = *(const uint4*)(Wt + c * 8);
    }
    __syncthreads();

    f32x4 acc[4][4];
    #pragma unroll
    for (int mi = 0; mi < 4; ++mi)
      #pragma unroll
      for (int ni = 0; ni < 4; ++ni) acc[mi][ni] = (f32x4){0.f, 0.f, 0.f, 0.f};

    #pragma unroll
    for (int kk = 0; kk < 4; ++kk) {
      bf16x8 af[4], bfr[4];
      #pragma unroll
      for (int mi = 0; mi < 4; ++mi) {
        int row = wm * 64 + mi * 16 + lr;
        int slot = (kk * 4 + lk) ^ (row & 7);
        af[mi] = *(const bf16x8*)(&At[row * 128 + slot * 8]);
      }
      #pragma unroll
      for (int ni = 0; ni < 4; ++ni) {
        int row = wn * 64 + ni * 16 + lr;
        int slot = (kk * 4 + lk) ^ (row & 7);
        bfr[ni] = *(const bf16x8*)(&Bt[row * 128 + slot * 8]);
      }
      #pragma unroll
      for (int mi = 0; mi < 4; ++mi)
        #pragma unroll
        for (int ni = 0; ni < 4; ++ni)
          acc[mi][ni] = __builtin_amdgcn_mfma_f32_16x16x32_bf16(af[mi], bfr[ni], acc[mi][ni], 0, 0, 0);
    }

    const float* bias = ga.b[which];
    float bv[4];
    #pragma unroll
    for (int ni = 0; ni < 4; ++ni) bv[ni] = bias[wn * 64 + ni * 16 + lr];
    #pragma unroll
    for (int mi = 0; mi < 4; ++mi) {
      #pragma unroll
      for (int i = 0; i < 4; ++i) {
        int row = m0 + wm * 64 + mi * 16 + lk * 4 + i;
        if (row < ga.M) {
          #pragma unroll
          for (int ni = 0; ni < 4; ++ni) {
            int col = wn * 64 + ni * 16 + lr;
            unsigned short val = f2bf(acc[mi][ni][i] + bv[ni]);
            if (which == 0)      ga.qb[(size_t)row * 128 + col] = val;
            else if (which == 3) ga.sb[(size_t)row * 128 + col] = val;
            else ga.kvb[(size_t)row * 256 + (size_t)(col >> 1) * 4 + (col & 1) + (which == 2 ? 2 : 0)] = val;
          }
        }
      }
    }
  }
}

// ---------------------------------------------------------------------------
// Per-dst-node fused attention v6: persistent grid-stride blocks, interleaved
// kv uint2 gathers, JIT ep stream loads, factored edge-MLP, 8-edge chunks,
// double-buffered. NO register cap (r7's (256,8) cap -> 32 VGPR -> 1GB spill).
// ---------------------------------------------------------------------------
template<int CHALF, bool RELU, bool OUT_BF16>
__global__ __launch_bounds__(256) void edge_attn(
    const unsigned short* __restrict__ Q, const uint2* __restrict__ KV,
    const unsigned short* __restrict__ S, const float* __restrict__ We,
    const unsigned short* __restrict__ EAC,
    const int* __restrict__ srcArr, const int* __restrict__ rs,
    void* __restrict__ outv, float inv_sqrt_c) {
  int wv = threadIdx.x >> 6, lane = threadIdx.x & 63;
  int c0 = lane * 2;
  int jbase = (lane & 1) * 8 + ((lane >> 1) & 1) * 4 + ((lane >> 2) & 1) * 2;

  for (int ng = blockIdx.x; ng < NGROUPS; ng += gridDim.x) {
    int node = ng * 4 + wv;   // NGROUPS*4 == N_NODES exactly

    unsigned int qp = *(const unsigned int*)(Q + (size_t)node * 128 + c0);
    float qa = bfl(qp) * inv_sqrt_c;
    float qb = bfh(qp) * inv_sqrt_c;

    // qWe[j] reduce-scatter over lane bits 0..2
    float part[16];
    #pragma unroll
    for (int j = 0; j < 16; ++j) {
      float2 wp = *(const float2*)(We + j * 128 + c0);
      part[j] = qa * wp.x + qb * wp.y;
    }
    {
      bool hi = lane & 1;
      #pragma unroll
      for (int j = 0; j < 8; ++j) {
        float kept = hi ? part[j + 8] : part[j];
        float sent = hi ? part[j] : part[j + 8];
        part[j] = kept + __shfl_xor(sent, 1, 64);
      }
      hi = lane & 2;
      #pragma unroll
      for (int j = 0; j < 4; ++j) {
        float kept = hi ? part[j + 4] : part[j];
        float sent = hi ? part[j] : part[j + 4];
        part[j] = kept + __shfl_xor(sent, 2, 64);
      }
      hi = lane & 4;
      #pragma unroll
      for (int j = 0; j < 2; ++j) {
        float kept = hi ? part[j + 2] : part[j];
        float sent = hi ? part[j] : part[j + 2];
        part[j] = kept + __shfl_xor(sent, 4, 64);
      }
    }
    if (CHALF == 64) {
      #pragma unroll
      for (int s = 8; s <= 32; s <<= 1) {
        part[0] += __shfl_xor(part[0], s, 64);
        part[1] += __shfl_xor(part[1], s, 64);
      }
    }
    float qw0 = part[0] * (CHALF == 64 ? 0.125f : 1.0f);
    float qw1 = part[1] * (CHALF == 64 ? 0.125f : 1.0f);

    int i0 = rs[node], i1 = rs[node + 1];
    int deg = i1 - i0;
    float den = 0.f, a0 = 0.f, a1 = 0.f, wea0 = 0.f, wea1 = 0.f;

    struct Buf { uint2 kv[8]; };
    Buf bA, bB;
    int svA = 0, svB = 0;

    auto load_src = [&](int c) -> int {
      return srcArr[i0 + c * 8 + (lane & 7)];
    };
    auto gather = [&](Buf& b, int sv) {
      #pragma unroll
      for (int j = 0; j < 8; ++j) {
        int s = __shfl(sv, j, 8);
        b.kv[j] = KV[(size_t)s * 64 + lane];
      }
    };
    auto compute = [&](const Buf& b, int c) {
      #pragma unroll
      for (int j = 0; j < 8; ++j) {
        int g = i0 + c * 8 + j;
        unsigned int ep = *(const unsigned int*)(EAC + (size_t)g * 16 + jbase);
        float ea0 = bfl(ep), ea1 = bfh(ep);
        float p = qa * bfl(b.kv[j].x) + qb * bfh(b.kv[j].x) + qw0 * ea0 + qw1 * ea1;
        #pragma unroll
        for (int off = 1; off < CHALF; off <<= 1) p += __shfl_xor(p, off, 64);
        float w = (g < i1) ? __expf(p) : 0.f;
        den  += w;
        a0   += w * bfl(b.kv[j].y);
        a1   += w * bfh(b.kv[j].y);
        wea0 += w * ea0;
        wea1 += w * ea1;
      }
    };

    int nch = (deg + 7) >> 3;
    if (nch > 0) {
      svA = load_src(0);
      if (nch > 1) svB = load_src(1);
      gather(bA, svA);
      int c = 0;
      while (true) {
        if (c + 1 < nch) gather(bB, svB);
        if (c + 2 < nch) svA = load_src(c + 2);
        compute(bA, c);
        ++c; if (c >= nch) break;
        if (c + 1 < nch) gather(bA, svA);
        if (c + 2 < nch) svB = load_src(c + 2);
        compute(bB, c);
        ++c; if (c >= nch) break;
      }
    }

    // epilogue: (a + wea@We)/den + skip
    float inv = 1.f / (den + 1e-16f);
    float eadd0 = 0.f, eadd1 = 0.f;
    #pragma unroll
    for (int j = 0; j < 16; ++j) {
      int owner = ((j >> 3) & 1) | (((j >> 2) & 1) << 1) | (((j >> 1) & 1) << 2);
      int srcl = (lane & 56) | owner;
      float val = __shfl((j & 1) ? wea1 : wea0, srcl, 64);
      float2 wp = *(const float2*)(We + j * 128 + c0);
      eadd0 += val * wp.x;
      eadd1 += val * wp.y;
    }
    unsigned int sp = *(const unsigned int*)(S + (size_t)node * 128 + c0);
    float o0 = (a0 + eadd0) * inv + bfl(sp);
    float o1 = (a1 + eadd1) * inv + bfh(sp);
    if (RELU) { o0 = fmaxf(o0, 0.f); o1 = fmaxf(o1, 0.f); }
    if (OUT_BF16) {
      unsigned int op = ((unsigned int)f2bf(o1) << 16) | (unsigned int)f2bf(o0);
      *(unsigned int*)((unsigned short*)outv + (size_t)node * 128 + c0) = op;
    } else {
      *(float2*)((float*)outv + (size_t)node * 128 + c0) = make_float2(o0, o1);
    }
  }
}

// ---------------------------------------------------------------------------
extern "C" void kernel_launch(void* const* d_in, const int* in_sizes, int n_in,
                              void* d_out, int out_size, void* d_ws, size_t ws_size,
                              hipStream_t stream) {
  const float* x   = (const float*)d_in[0];
  const int*   ei  = (const int*)d_in[1];
  const float* ea  = (const float*)d_in[2];
  const float* Wq0 = (const float*)d_in[3];
  const float* bq0 = (const float*)d_in[4];
  const float* Wk0 = (const float*)d_in[5];
  const float* bk0 = (const float*)d_in[6];
  const float* Wv0 = (const float*)d_in[7];
  const float* bv0 = (const float*)d_in[8];
  const float* We0 = (const float*)d_in[9];
  const float* Ws0 = (const float*)d_in[10];
  const float* bs0 = (const float*)d_in[11];
  const float* Wq1 = (const float*)d_in[12];
  const float* bq1 = (const float*)d_in[13];
  const float* Wk1 = (const float*)d_in[14];
  const float* bk1 = (const float*)d_in[15];
  const float* Wv1 = (const float*)d_in[16];
  const float* bv1 = (const float*)d_in[17];
  const float* We1 = (const float*)d_in[18];
  const float* Ws1 = (const float*)d_in[19];
  const float* bs1 = (const float*)d_in[20];

  char* ws = (char*)d_ws;
  size_t off = 0;
  auto alloc = [&](size_t bytes) -> void* {
    void* p = ws + off;
    off = (off + bytes + 255) & ~(size_t)255;
    return p;
  };
  unsigned short* WT    = (unsigned short*)alloc(8 * 16384 * 2);
  unsigned short* q     = (unsigned short*)alloc((size_t)N_NODES * 128 * 2);
  unsigned short* kvb   = (unsigned short*)alloc((size_t)N_NODES * 256 * 2);
  unsigned short* s     = (unsigned short*)alloc((size_t)N_NODES * 128 * 2);
  unsigned short* h     = (unsigned short*)alloc((size_t)N_NODES * 128 * 2);
  unsigned short* eacsr = (unsigned short*)alloc(((size_t)N_EDGES + 8) * 16 * 2);
  int* cc     = (int*)alloc((size_t)2 * N_NODES * 4);      // cnt | cursor
  int* rs     = (int*)alloc((N_NODES + 1) * 4);
  int* srcArr = (int*)alloc(((size_t)N_EDGES + 8) * 4);
  int* cnt = cc, *cursor = cc + N_NODES;
  // total ~94 MB

  const int* srcp = ei;
  const int* dstp = ei + N_EDGES;

  hipMemsetAsync(cc, 0, (size_t)2 * N_NODES * 4, stream);
  hipMemsetAsync(srcArr + N_EDGES, 0, 8 * 4, stream);
  hipMemsetAsync(eacsr + (size_t)N_EDGES * 16, 0, 8 * 16 * 2, stream);

  Ptr8 p8 = {{Wq0, Wk0, Wv0, Ws0, Wq1, Wk1, Wv1, Ws1}};
  transpose_w<<<8, 256, 0, stream>>>(p8, WT);
  hist_kernel<<<3125, 256, 0, stream>>>(dstp, cnt);
  scan_kernel<<<1, 1024, 0, stream>>>(cnt, rs);
  scatter_kernel<<<3125, 256, 0, stream>>>(srcp, dstp, ea, rs, cursor, srcArr, eacsr);

  // layer 0
  Gemm4Args ga0 = { x, nullptr, WT, {bq0, bk0, bv0, bs0}, q, kvb, s, N_NODES };
  node_gemm4<true><<<391, 256, 0, stream>>>(ga0);
  edge_attn<8, true, true><<<2048, 256, 0, stream>>>(q, (const uint2*)kvb, s, We0, eacsr,
                                                     srcArr, rs, h, 0.25f);

  // layer 1
  Gemm4Args ga1 = { nullptr, h, WT + 4 * 16384, {bq1, bk1, bv1, bs1}, q, kvb, s, N_NODES };
  node_gemm4<false><<<391, 256, 0, stream>>>(ga1);
  edge_attn<64, false, false><<<2048, 256, 0, stream>>>(q, (const uint2*)kvb, s, We1, eacsr,
                                                        srcArr, rs, d_out, 0.08838834764831845f);
}